// Round 13
// baseline (61.825 us; speedup 1.0000x reference)
//
#include <hip/hip_runtime.h>
#include <stdint.h>

#define B_ 4
#define C_ 512
#define N_ 4096
#define D_ 64
#define LOG2E 1.4426950408889634f

typedef __attribute__((ext_vector_type(8))) short short8;
typedef __attribute__((ext_vector_type(4))) float f32x4;
typedef __attribute__((ext_vector_type(16))) float f32x16;
typedef unsigned short ushort_t;

static __device__ __forceinline__ ushort_t f2bf(float f) {
    union { float f; uint32_t u; } v; v.f = f;
    uint32_t u = v.u;
    uint32_t r = u + 0x7FFFu + ((u >> 16) & 1u);
    return (ushort_t)(r >> 16);
}
static __device__ __forceinline__ float bf2f(uint32_t u) {
    union { uint32_t u; float f; } v; v.u = u << 16;
    return v.f;
}
static __device__ __forceinline__ uint32_t cvtpk_bf16(float lo, float hi) {
    uint32_t r;
    asm("v_cvt_pk_bf16_f32 %0, %1, %2" : "=v"(r) : "v"(lo), "v"(hi));
    return r;
}
// async global->LDS, 16B per lane. LDS dst must be wave-uniform base + lane*16.
static __device__ __forceinline__ void gl16(const ushort_t* g, ushort_t* l) {
    __builtin_amdgcn_global_load_lds(
        (const __attribute__((address_space(1))) void*)g,
        (__attribute__((address_space(3))) void*)l, 16, 0, 0);
}

// -------------------------------------------------------------------------
// Kernel 1: merged F/G/H projections, 32-loc tiles, LDS DOUBLE-BUFFERED
// k-loop: one barrier per chunk (16 total, was 32). Verified epilogue
// layouts unchanged (bounce buffers now in As[0]/Bs[0], disjoint).
// -------------------------------------------------------------------------
__global__ __launch_bounds__(512) void proj_fgh(
    const float* __restrict__ x,
    const float* __restrict__ wf, const float* __restrict__ bf,
    const float* __restrict__ wg, const float* __restrict__ bg,
    const float* __restrict__ wh, const float* __restrict__ bh,
    ushort_t* __restrict__ Ftf, ushort_t* __restrict__ Gt,
    ushort_t* __restrict__ Vtf)
{
    const int b    = blockIdx.y;
    const int nb   = blockIdx.x;           // 0..127
    const int tile = nb >> 1;              // 64-key tile index
    const int cc   = nb & 1;               // which 32-half of the tile
    const int n0   = nb * 32;
    const int tid  = threadIdx.x;          // 0..511
    const int wv   = tid >> 6;             // 0..7
    const int mw   = wv & 1;               // m-tile (16 locs)
    const int hi   = wv >> 1;              // o-group 0..3
    const int lane = tid & 63;
    const int g    = lane >> 4;
    const int r    = lane & 15;

    __shared__ ushort_t As[2][32][40];     // [buf][loc][k]
    __shared__ ushort_t Bs[2][192][40];    // [buf][o][k]

    f32x4 acc[3];
    #pragma unroll
    for (int t = 0; t < 3; ++t) acc[t] = (f32x4){0.f, 0.f, 0.f, 0.f};

    const int ka = tid >> 4;               // 0..31 (k row)
    const int mb = (tid & 15) * 2;         // 0..30 (2 locs)
    const int ow = tid >> 3;               // 0..63 (o row within group)
    const int kb = (tid & 7) * 4;          // 0..28

    const float* xp  = x  + ((size_t)b * C_ + ka) * N_ + n0 + mb;
    const float* wp0 = wf + (size_t)ow * C_ + kb;
    const float* wp1 = wg + (size_t)ow * C_ + kb;
    const float* wp2 = wh + (size_t)ow * C_ + kb;

    // chunk 0 into regs, stage into buf 0
    float2 xa = *(const float2*)xp;
    float4 w0 = *(const float4*)wp0;
    float4 w1 = *(const float4*)wp1;
    float4 w2 = *(const float4*)wp2;
    As[0][mb + 0][ka] = f2bf(xa.x);
    As[0][mb + 1][ka] = f2bf(xa.y);
    {
        uint2 p0, p1, p2;
        p0.x = cvtpk_bf16(w0.x, w0.y); p0.y = cvtpk_bf16(w0.z, w0.w);
        p1.x = cvtpk_bf16(w1.x, w1.y); p1.y = cvtpk_bf16(w1.z, w1.w);
        p2.x = cvtpk_bf16(w2.x, w2.y); p2.y = cvtpk_bf16(w2.z, w2.w);
        *(uint2*)&Bs[0][ow][kb]       = p0;
        *(uint2*)&Bs[0][64 + ow][kb]  = p1;
        *(uint2*)&Bs[0][128 + ow][kb] = p2;
    }
    // prefetch chunk 1
    xa = *(const float2*)(xp + (size_t)32 * N_);
    w0 = *(const float4*)(wp0 + 32);
    w1 = *(const float4*)(wp1 + 32);
    w2 = *(const float4*)(wp2 + 32);
    __syncthreads();

    for (int c = 0; c < 16; ++c) {
        const int cur = c & 1;
        if (c + 1 < 16) {
            const int nx = cur ^ 1;
            // stage chunk c+1 (regs already loaded)
            As[nx][mb + 0][ka] = f2bf(xa.x);
            As[nx][mb + 1][ka] = f2bf(xa.y);
            uint2 p0, p1, p2;
            p0.x = cvtpk_bf16(w0.x, w0.y); p0.y = cvtpk_bf16(w0.z, w0.w);
            p1.x = cvtpk_bf16(w1.x, w1.y); p1.y = cvtpk_bf16(w1.z, w1.w);
            p2.x = cvtpk_bf16(w2.x, w2.y); p2.y = cvtpk_bf16(w2.z, w2.w);
            *(uint2*)&Bs[nx][ow][kb]       = p0;
            *(uint2*)&Bs[nx][64 + ow][kb]  = p1;
            *(uint2*)&Bs[nx][128 + ow][kb] = p2;
            if (c + 2 < 16) {
                const int k2 = (c + 2) * 32;
                xa = *(const float2*)(xp + (size_t)k2 * N_);
                w0 = *(const float4*)(wp0 + k2);
                w1 = *(const float4*)(wp1 + k2);
                w2 = *(const float4*)(wp2 + k2);
            }
        }
        short8 a = *(const short8*)&As[cur][16 * mw + r][8 * g];
        __builtin_amdgcn_s_setprio(1);
        #pragma unroll
        for (int tt = 0; tt < 3; ++tt) {
            const int T = tt * 4 + hi;
            short8 bbv = *(const short8*)&Bs[cur][T * 16 + r][8 * g];
            acc[tt] = __builtin_amdgcn_mfma_f32_16x16x32_bf16(a, bbv, acc[tt], 0, 0, 0);
        }
        __builtin_amdgcn_s_setprio(0);
        __syncthreads();   // next buf staged & current buf reads done
    }

    // ---- G (tt=1): direct store, o = hi*16 + r
    {
        const int og = hi * 16 + r;
        const float bvv = bg[og];
        #pragma unroll
        for (int j = 0; j < 4; ++j) {
            const int loc = n0 + 16 * mw + 4 * g + j;
            Gt[((size_t)b * N_ + loc) * D_ + og] = f2bf(acc[1][j] + bvv);
        }
    }

    // ---- bounce buffers (disjoint regions, all k-loop reads complete)
    ushort_t (*bbF)[72] = (ushort_t(*)[72])&As[0][0][0];   // 32x72 <= 2x32x40
    ushort_t (*bbH)[72] = (ushort_t(*)[72])&Bs[0][0][0];   // 32x72 <= 2x192x40

    {
        const int o = hi * 16 + r;
        const float bvv = bf[o];
        #pragma unroll
        for (int j = 0; j < 4; ++j)
            bbF[16 * mw + 4 * g + j][o] = f2bf((acc[0][j] + bvv) * LOG2E);
    }
    {
        const int o = hi * 16 + r;
        const float bvv = bh[o];
        #pragma unroll
        for (int j = 0; j < 4; ++j)
            bbH[16 * mw + 4 * g + j][o] = f2bf(acc[2][j] + bvv);
    }
    __syncthreads();

    if (tid < 256) {
        const int s = (tid >> 6) & 3;          // d-slab
        const int l = tid & 63;
        short8 v = *(const short8*)&bbF[l & 31][16 * s + 8 * (l >> 5)];
        const int f = cc * 4 + s;
        *(short8*)&Ftf[(((size_t)b * 64 + tile) * 8 + f) * 512 + l * 8] = v;
    } else {
        const int u   = tid & 255;
        const int fi  = u >> 6;                // sub*2 + dt
        const int sub = fi >> 1, dt = fi & 1;
        const int l   = u & 63;
        const int h2l = l >> 5;
        short8 v;
        #pragma unroll
        for (int e = 0; e < 8; ++e) {
            const int i = 16 * sub + (e & 3) + 8 * (e >> 2) + 4 * h2l;
            v[e] = (short)bbH[i][32 * dt + (l & 31)];
        }
        const int f = cc * 4 + sub * 2 + dt;
        *(short8*)&Vtf[(((size_t)b * 64 + tile) * 8 + f) * 512 + l * 8] = v;
    }
}

// -------------------------------------------------------------------------
// Kernel 2: flash attention (R12 exact — best measured; unchanged).
// -------------------------------------------------------------------------
__global__ __launch_bounds__(256, 4) void attn(
    const ushort_t* __restrict__ Ftf, const ushort_t* __restrict__ Gt,
    const ushort_t* __restrict__ Vtf,
    ushort_t* __restrict__ Op, float* __restrict__ ml, int ksplit)
{
    const int b    = blockIdx.z;
    const int part = blockIdx.y;
    const int tid  = threadIdx.x;
    const int lane = tid & 63;
    const int wave = tid >> 6;
    const int l31  = lane & 31;
    const int h2   = lane >> 5;
    const int j0   = blockIdx.x * 128 + wave * 32;
    const int NT   = (N_ / ksplit) / 64;
    const int kt0  = part * NT;
    const int t0   = (blockIdx.x * 5 + part * 3 + b) & (NT - 1);

    __shared__ __align__(16) ushort_t Ks[2][4096];
    __shared__ __align__(16) ushort_t Vs[2][4096];

    const ushort_t* qrow = Gt + ((size_t)b * N_ + j0 + l31) * D_ + 8 * h2;
    const short8 qf0 = *(const short8*)(qrow);
    const short8 qf1 = *(const short8*)(qrow + 16);
    const short8 qf2 = *(const short8*)(qrow + 32);
    const short8 qf3 = *(const short8*)(qrow + 48);

    const ushort_t* Kt = Ftf + ((size_t)b * 64 + kt0) * 4096;
    const ushort_t* Vt = Vtf + ((size_t)b * 64 + kt0) * 4096;

    f32x16 oA, oB;
    #pragma unroll
    for (int q = 0; q < 16; ++q) { oA[q] = 0.f; oB[q] = 0.f; }
    float l_run = 0.f;

    {
        const size_t off = (size_t)t0 * 4096;
        gl16(Kt + off + tid * 8,         &Ks[0][tid * 8]);
        gl16(Kt + off + (tid + 256) * 8, &Ks[0][(tid + 256) * 8]);
        gl16(Vt + off + tid * 8,         &Vs[0][tid * 8]);
        gl16(Vt + off + (tid + 256) * 8, &Vs[0][(tid + 256) * 8]);
    }

    int buf = 0;
    for (int t = 0; t < NT; ++t) {
        __syncthreads();   // drains current tile's DMA (issued a full iter ago)
        if (t + 1 < NT) {
            int nt = t + 1 + t0; if (nt >= NT) nt -= NT;
            const ushort_t* kg = Kt + (size_t)nt * 4096;
            const ushort_t* vg = Vt + (size_t)nt * 4096;
            const int nb = buf ^ 1;
            gl16(kg + tid * 8,         &Ks[nb][tid * 8]);
            gl16(kg + (tid + 256) * 8, &Ks[nb][(tid + 256) * 8]);
            gl16(vg + tid * 8,         &Vs[nb][tid * 8]);
            gl16(vg + (tid + 256) * 8, &Vs[nb][(tid + 256) * 8]);
        }

        const ushort_t* kb0 = &Ks[buf][0];
        const ushort_t* kb1 = &Ks[buf][2048];
        const ushort_t* vb0 = &Vs[buf][0];
        const ushort_t* vb1 = &Vs[buf][2048];

        f32x16 sx0, sx1;
        #pragma unroll
        for (int q = 0; q < 16; ++q) { sx0[q] = 0.f; sx1[q] = 0.f; }
        __builtin_amdgcn_s_setprio(1);
        {
            const short8 ka0 = *(const short8*)(kb0 + 0 * 512 + lane * 8);
            sx0 = __builtin_amdgcn_mfma_f32_32x32x16_bf16(ka0, qf0, sx0, 0, 0, 0);
            const short8 ka1 = *(const short8*)(kb0 + 1 * 512 + lane * 8);
            sx0 = __builtin_amdgcn_mfma_f32_32x32x16_bf16(ka1, qf1, sx0, 0, 0, 0);
            const short8 ka2 = *(const short8*)(kb0 + 2 * 512 + lane * 8);
            sx0 = __builtin_amdgcn_mfma_f32_32x32x16_bf16(ka2, qf2, sx0, 0, 0, 0);
            const short8 ka3 = *(const short8*)(kb0 + 3 * 512 + lane * 8);
            sx0 = __builtin_amdgcn_mfma_f32_32x32x16_bf16(ka3, qf3, sx0, 0, 0, 0);
            const short8 kb0f = *(const short8*)(kb1 + 0 * 512 + lane * 8);
            sx1 = __builtin_amdgcn_mfma_f32_32x32x16_bf16(kb0f, qf0, sx1, 0, 0, 0);
            const short8 kb1f = *(const short8*)(kb1 + 1 * 512 + lane * 8);
            sx1 = __builtin_amdgcn_mfma_f32_32x32x16_bf16(kb1f, qf1, sx1, 0, 0, 0);
            const short8 kb2f = *(const short8*)(kb1 + 2 * 512 + lane * 8);
            sx1 = __builtin_amdgcn_mfma_f32_32x32x16_bf16(kb2f, qf2, sx1, 0, 0, 0);
            const short8 kb3f = *(const short8*)(kb1 + 3 * 512 + lane * 8);
            sx1 = __builtin_amdgcn_mfma_f32_32x32x16_bf16(kb3f, qf3, sx1, 0, 0, 0);
        }
        __builtin_amdgcn_s_setprio(0);

        float cs0 = 0.f;
        union { uint32_t w[4]; short8 v; } p00, p01;
        {
            uint32_t pw[8];
            #pragma unroll
            for (int q = 0; q < 8; ++q) {
                const float pa = __builtin_amdgcn_exp2f(sx0[2 * q]);
                const float pb = __builtin_amdgcn_exp2f(sx0[2 * q + 1]);
                cs0 += pa + pb;
                pw[q] = cvtpk_bf16(pa, pb);
            }
            p00.w[0] = pw[0]; p00.w[1] = pw[1]; p00.w[2] = pw[2]; p00.w[3] = pw[3];
            p01.w[0] = pw[4]; p01.w[1] = pw[5]; p01.w[2] = pw[6]; p01.w[3] = pw[7];
        }

        __builtin_amdgcn_s_setprio(1);
        {
            const short8 v00 = *(const short8*)(vb0 + 0 * 512 + lane * 8);
            oA = __builtin_amdgcn_mfma_f32_32x32x16_bf16(v00, p00.v, oA, 0, 0, 0);
            const short8 v01 = *(const short8*)(vb0 + 1 * 512 + lane * 8);
            oB = __builtin_amdgcn_mfma_f32_32x32x16_bf16(v01, p00.v, oB, 0, 0, 0);
            const short8 v10 = *(const short8*)(vb0 + 2 * 512 + lane * 8);
            oA = __builtin_amdgcn_mfma_f32_32x32x16_bf16(v10, p01.v, oA, 0, 0, 0);
            const short8 v11 = *(const short8*)(vb0 + 3 * 512 + lane * 8);
            oB = __builtin_amdgcn_mfma_f32_32x32x16_bf16(v11, p01.v, oB, 0, 0, 0);
        }
        __builtin_amdgcn_s_setprio(0);

        float cs1 = 0.f;
        union { uint32_t w[4]; short8 v; } p10, p11;
        {
            uint32_t pw[8];
            #pragma unroll
            for (int q = 0; q < 8; ++q) {
                const float pa = __builtin_amdgcn_exp2f(sx1[2 * q]);
                const float pb = __builtin_amdgcn_exp2f(sx1[2 * q + 1]);
                cs1 += pa + pb;
                pw[q] = cvtpk_bf16(pa, pb);
            }
            p10.w[0] = pw[0]; p10.w[1] = pw[1]; p10.w[2] = pw[2]; p10.w[3] = pw[3];
            p11.w[0] = pw[4]; p11.w[1] = pw[5]; p11.w[2] = pw[6]; p11.w[3] = pw[7];
        }

        __builtin_amdgcn_s_setprio(1);
        {
            const short8 v00 = *(const short8*)(vb1 + 0 * 512 + lane * 8);
            oA = __builtin_amdgcn_mfma_f32_32x32x16_bf16(v00, p10.v, oA, 0, 0, 0);
            const short8 v01 = *(const short8*)(vb1 + 1 * 512 + lane * 8);
            oB = __builtin_amdgcn_mfma_f32_32x32x16_bf16(v01, p10.v, oB, 0, 0, 0);
            const short8 v10 = *(const short8*)(vb1 + 2 * 512 + lane * 8);
            oA = __builtin_amdgcn_mfma_f32_32x32x16_bf16(v10, p11.v, oA, 0, 0, 0);
            const short8 v11 = *(const short8*)(vb1 + 3 * 512 + lane * 8);
            oB = __builtin_amdgcn_mfma_f32_32x32x16_bf16(v11, p11.v, oB, 0, 0, 0);
        }
        __builtin_amdgcn_s_setprio(0);

        l_run += cs0 + cs1;
        buf ^= 1;
    }

    const float lt = l_run + __shfl_xor(l_run, 32);

    ushort_t* orow = Op + (((size_t)b * ksplit + part) * N_ + j0 + l31) * D_;
    #pragma unroll
    for (int q = 0; q < 4; ++q) {
        const int d0 = 8 * q + 4 * h2;
        uint2 ua, ub;
        ua.x = cvtpk_bf16(oA[4 * q],     oA[4 * q + 1]);
        ua.y = cvtpk_bf16(oA[4 * q + 2], oA[4 * q + 3]);
        *(uint2*)&orow[d0] = ua;
        ub.x = cvtpk_bf16(oB[4 * q],     oB[4 * q + 1]);
        ub.y = cvtpk_bf16(oB[4 * q + 2], oB[4 * q + 3]);
        *(uint2*)&orow[32 + d0] = ub;
    }
    if (h2 == 0)
        ml[((size_t)b * ksplit + part) * N_ + j0 + l31] = lt;
}

// -------------------------------------------------------------------------
// Kernel 3: fused reduce + outproj, 32-LOC TILES (grid 512 = 2 blocks/CU;
// was 1 block/CU). Same verified math; t-loop 4 -> 2.
// -------------------------------------------------------------------------
__global__ __launch_bounds__(512) void reduce_outproj(
    const ushort_t* __restrict__ Op, const float* __restrict__ ml,
    const float* __restrict__ wv, const float* __restrict__ bv,
    const float* __restrict__ gamma, const float* __restrict__ x,
    float* __restrict__ y, int ksplit)
{
    const int b    = blockIdx.y;
    const int n0   = blockIdx.x * 32;
    const int tid  = threadIdx.x;          // 0..511
    const int wv8  = tid >> 6;             // wave 0..7 -> co rows [wv8*64, +64)
    const int lane = tid & 63;
    const int g    = lane >> 4;
    const int r    = lane & 15;

    __shared__ ushort_t Os[32][72];        // [loc][k] normalized O tile

    // ---- phase 1: reduce partials (16 threads per loc, 4 k each)
    {
        const int loc = tid >> 4;          // 0..31
        const int k4  = (tid & 15) * 4;    // 0..60
        float L = 0.f;
        float v0 = 0.f, v1 = 0.f, v2 = 0.f, v3 = 0.f;
        for (int p = 0; p < ksplit; ++p) {
            const size_t base = ((size_t)b * ksplit + p) * N_ + n0 + loc;
            L += ml[base];
            uint2 u = *(const uint2*)&Op[base * D_ + k4];
            v0 += bf2f(u.x & 0xffffu); v1 += bf2f(u.x >> 16);
            v2 += bf2f(u.y & 0xffffu); v3 += bf2f(u.y >> 16);
        }
        const float inv = 1.0f / L;
        uint2 o;
        o.x = cvtpk_bf16(v0 * inv, v1 * inv);
        o.y = cvtpk_bf16(v2 * inv, v3 * inv);
        *(uint2*)&Os[loc][k4] = o;
    }
    __syncthreads();

    // ---- phase 2: wave wv8 projects its 64 co rows against the 32-loc tile
    short8 a[4][2];
    #pragma unroll
    for (int cs = 0; cs < 4; ++cs) {
        const float* wrow = wv + (size_t)(wv8 * 64 + cs * 16 + r) * D_ + 8 * g;
        const float4 wa = *(const float4*)(wrow);
        const float4 wb = *(const float4*)(wrow + 4);
        const float4 wc = *(const float4*)(wrow + 32);
        const float4 wd = *(const float4*)(wrow + 36);
        uint32_t* a0 = (uint32_t*)&a[cs][0];
        uint32_t* a1 = (uint32_t*)&a[cs][1];
        a0[0] = cvtpk_bf16(wa.x, wa.y); a0[1] = cvtpk_bf16(wa.z, wa.w);
        a0[2] = cvtpk_bf16(wb.x, wb.y); a0[3] = cvtpk_bf16(wb.z, wb.w);
        a1[0] = cvtpk_bf16(wc.x, wc.y); a1[1] = cvtpk_bf16(wc.z, wc.w);
        a1[2] = cvtpk_bf16(wd.x, wd.y); a1[3] = cvtpk_bf16(wd.z, wd.w);
    }

    f32x4 acc[4][2];
    #pragma unroll
    for (int cs = 0; cs < 4; ++cs)
        #pragma unroll
        for (int t = 0; t < 2; ++t) acc[cs][t] = (f32x4){0.f, 0.f, 0.f, 0.f};

    #pragma unroll
    for (int t = 0; t < 2; ++t) {
        const short8 b0 = *(const short8*)&Os[16 * t + r][8 * g];
        const short8 b1 = *(const short8*)&Os[16 * t + r][32 + 8 * g];
        __builtin_amdgcn_s_setprio(1);
        #pragma unroll
        for (int cs = 0; cs < 4; ++cs) {
            acc[cs][t] = __builtin_amdgcn_mfma_f32_16x16x32_bf16(a[cs][0], b0, acc[cs][t], 0, 0, 0);
            acc[cs][t] = __builtin_amdgcn_mfma_f32_16x16x32_bf16(a[cs][1], b1, acc[cs][t], 0, 0, 0);
        }
        __builtin_amdgcn_s_setprio(0);
    }

    const float gm = *gamma;
    #pragma unroll
    for (int cs = 0; cs < 4; ++cs) {
        #pragma unroll
        for (int t = 0; t < 2; ++t) {
            #pragma unroll
            for (int j = 0; j < 4; ++j) {
                const int co = wv8 * 64 + cs * 16 + 4 * g + j;
                const int n  = n0 + 16 * t + r;
                const size_t idx = ((size_t)b * C_ + co) * N_ + n;
                y[idx] = gm * (acc[cs][t][j] + bv[co]) + x[idx];
            }
        }
    }
}

// -------------------------------------------------------------------------
extern "C" void kernel_launch(void* const* d_in, const int* in_sizes, int n_in,
                              void* d_out, int out_size, void* d_ws, size_t ws_size,
                              hipStream_t stream) {
    const float* x     = (const float*)d_in[0];
    const float* wf    = (const float*)d_in[1];
    const float* bf    = (const float*)d_in[2];
    const float* wg    = (const float*)d_in[3];
    const float* bg    = (const float*)d_in[4];
    const float* wh    = (const float*)d_in[5];
    const float* bh    = (const float*)d_in[6];
    const float* wv    = (const float*)d_in[7];
    const float* bv    = (const float*)d_in[8];
    const float* gamma = (const float*)d_in[9];
    float* y = (float*)d_out;

    const size_t plane = (size_t)B_ * N_ * D_;   // 1M elements
    ushort_t* Ftf = (ushort_t*)d_ws;             // pre-swizzled K fragments
    ushort_t* Gt  = Ftf + plane;                 // Q rows
    ushort_t* Vtf = Gt + plane;                  // pre-swizzled V fragments
    ushort_t* Op  = Vtf + plane;                 // split-K partials (bf16)

    int KS = 8;
    while (KS > 1) {
        const size_t need = 3 * plane * 2 + (size_t)KS * plane * 2
                          + (size_t)B_ * KS * N_ * sizeof(float);
        if (need <= ws_size) break;
        KS >>= 1;
    }
    float* ml = (float*)(Op + (size_t)KS * plane);

    proj_fgh<<<dim3(N_ / 32, B_), 512, 0, stream>>>(
        x, wf, bf, wg, bg, wh, bh, Ftf, Gt, Vtf);
    attn<<<dim3(N_ / 128, KS, B_), 256, 0, stream>>>(
        Ftf, Gt, Vtf, Op, ml, KS);
    reduce_outproj<<<dim3(N_ / 32, B_), 512, 0, stream>>>(
        Op, ml, wv, bv, gamma, x, y, KS);
}

// Round 14
// 58.573 us; speedup vs baseline: 1.0555x; 1.0555x over previous
//
#include <hip/hip_runtime.h>
#include <stdint.h>

#define B_ 4
#define C_ 512
#define N_ 4096
#define D_ 64
#define LOG2E 1.4426950408889634f

typedef __attribute__((ext_vector_type(8))) short short8;
typedef __attribute__((ext_vector_type(4))) float f32x4;
typedef __attribute__((ext_vector_type(16))) float f32x16;
typedef unsigned short ushort_t;

static __device__ __forceinline__ ushort_t f2bf(float f) {
    union { float f; uint32_t u; } v; v.f = f;
    uint32_t u = v.u;
    uint32_t r = u + 0x7FFFu + ((u >> 16) & 1u);
    return (ushort_t)(r >> 16);
}
static __device__ __forceinline__ float bf2f(uint32_t u) {
    union { uint32_t u; float f; } v; v.u = u << 16;
    return v.f;
}
static __device__ __forceinline__ uint32_t cvtpk_bf16(float lo, float hi) {
    uint32_t r;
    asm("v_cvt_pk_bf16_f32 %0, %1, %2" : "=v"(r) : "v"(lo), "v"(hi));
    return r;
}
// async global->LDS, 16B per lane. LDS dst must be wave-uniform base + lane*16.
static __device__ __forceinline__ void gl16(const ushort_t* g, ushort_t* l) {
    __builtin_amdgcn_global_load_lds(
        (const __attribute__((address_space(1))) void*)g,
        (__attribute__((address_space(3))) void*)l, 16, 0, 0);
}

// -------------------------------------------------------------------------
// Kernel 1: merged F/G/H projections, 32-loc tiles (R10/R12 config — best
// measured). F gets LOG2E folded; F -> Ftf, H -> Vtf in attn-fragment order.
// -------------------------------------------------------------------------
__global__ __launch_bounds__(512) void proj_fgh(
    const float* __restrict__ x,
    const float* __restrict__ wf, const float* __restrict__ bf,
    const float* __restrict__ wg, const float* __restrict__ bg,
    const float* __restrict__ wh, const float* __restrict__ bh,
    ushort_t* __restrict__ Ftf, ushort_t* __restrict__ Gt,
    ushort_t* __restrict__ Vtf)
{
    const int b    = blockIdx.y;
    const int nb   = blockIdx.x;           // 0..127
    const int tile = nb >> 1;              // 64-key tile index
    const int cc   = nb & 1;               // which 32-half of the tile
    const int n0   = nb * 32;
    const int tid  = threadIdx.x;          // 0..511
    const int wv   = tid >> 6;             // 0..7
    const int mw   = wv & 1;               // m-tile (16 locs)
    const int hi   = wv >> 1;              // o-group 0..3
    const int lane = tid & 63;
    const int g    = lane >> 4;
    const int r    = lane & 15;

    __shared__ ushort_t As[32][40];        // [loc][k]
    __shared__ ushort_t Bs[192][40];       // [o][k]

    f32x4 acc[3];
    #pragma unroll
    for (int t = 0; t < 3; ++t) acc[t] = (f32x4){0.f, 0.f, 0.f, 0.f};

    const int ka = tid >> 4;               // 0..31 (k row)
    const int mb = (tid & 15) * 2;         // 0..30 (2 locs)
    const int ow = tid >> 3;               // 0..63 (o row within group)
    const int kb = (tid & 7) * 4;          // 0..28

    const float* xp  = x  + ((size_t)b * C_ + ka) * N_ + n0 + mb;
    const float* wp0 = wf + (size_t)ow * C_ + kb;
    const float* wp1 = wg + (size_t)ow * C_ + kb;
    const float* wp2 = wh + (size_t)ow * C_ + kb;

    float2 xa = *(const float2*)xp;
    float4 w0 = *(const float4*)wp0;
    float4 w1 = *(const float4*)wp1;
    float4 w2 = *(const float4*)wp2;

    for (int k0 = 0; k0 < C_; k0 += 32) {
        As[mb + 0][ka] = f2bf(xa.x);
        As[mb + 1][ka] = f2bf(xa.y);
        {
            uint2 p0, p1, p2;
            p0.x = cvtpk_bf16(w0.x, w0.y); p0.y = cvtpk_bf16(w0.z, w0.w);
            p1.x = cvtpk_bf16(w1.x, w1.y); p1.y = cvtpk_bf16(w1.z, w1.w);
            p2.x = cvtpk_bf16(w2.x, w2.y); p2.y = cvtpk_bf16(w2.z, w2.w);
            *(uint2*)&Bs[ow][kb]       = p0;
            *(uint2*)&Bs[64 + ow][kb]  = p1;
            *(uint2*)&Bs[128 + ow][kb] = p2;
        }
        if (k0 + 32 < C_) {
            xa = *(const float2*)(xp + (size_t)(k0 + 32) * N_);
            w0 = *(const float4*)(wp0 + k0 + 32);
            w1 = *(const float4*)(wp1 + k0 + 32);
            w2 = *(const float4*)(wp2 + k0 + 32);
        }
        __syncthreads();
        short8 a = *(const short8*)&As[16 * mw + r][8 * g];
        __builtin_amdgcn_s_setprio(1);
        #pragma unroll
        for (int tt = 0; tt < 3; ++tt) {
            const int T = tt * 4 + hi;
            short8 bbv = *(const short8*)&Bs[T * 16 + r][8 * g];
            acc[tt] = __builtin_amdgcn_mfma_f32_16x16x32_bf16(a, bbv, acc[tt], 0, 0, 0);
        }
        __builtin_amdgcn_s_setprio(0);
        __syncthreads();
    }

    // ---- G (tt=1): direct store, o = hi*16 + r
    {
        const int og = hi * 16 + r;
        const float bvv = bg[og];
        #pragma unroll
        for (int j = 0; j < 4; ++j) {
            const int loc = n0 + 16 * mw + 4 * g + j;
            Gt[((size_t)b * N_ + loc) * D_ + og] = f2bf(acc[1][j] + bvv);
        }
    }

    ushort_t (*bbF)[72] = (ushort_t(*)[72])&Bs[0][0];
    ushort_t (*bbH)[72] = (ushort_t(*)[72])(&Bs[0][0] + 32 * 72);

    {
        const int o = hi * 16 + r;
        const float bvv = bf[o];
        #pragma unroll
        for (int j = 0; j < 4; ++j)
            bbF[16 * mw + 4 * g + j][o] = f2bf((acc[0][j] + bvv) * LOG2E);
    }
    {
        const int o = hi * 16 + r;
        const float bvv = bh[o];
        #pragma unroll
        for (int j = 0; j < 4; ++j)
            bbH[16 * mw + 4 * g + j][o] = f2bf(acc[2][j] + bvv);
    }
    __syncthreads();

    if (tid < 256) {
        const int s = (tid >> 6) & 3;          // d-slab
        const int l = tid & 63;
        short8 v = *(const short8*)&bbF[l & 31][16 * s + 8 * (l >> 5)];
        const int f = cc * 4 + s;
        *(short8*)&Ftf[(((size_t)b * 64 + tile) * 8 + f) * 512 + l * 8] = v;
    } else {
        const int u   = tid & 255;
        const int fi  = u >> 6;                // sub*2 + dt
        const int sub = fi >> 1, dt = fi & 1;
        const int l   = u & 63;
        const int h2l = l >> 5;
        short8 v;
        #pragma unroll
        for (int e = 0; e < 8; ++e) {
            const int i = 16 * sub + (e & 3) + 8 * (e >> 2) + 4 * h2l;
            v[e] = (short)bbH[i][32 * dt + (l & 31)];
        }
        const int f = cc * 4 + sub * 2 + dt;
        *(short8*)&Vtf[(((size_t)b * 64 + tile) * 8 + f) * 512 + l * 8] = v;
    }
}

// -------------------------------------------------------------------------
// Kernel 2: flash attention (R12 exact — best measured).
// 32x32x16 MFMA, split-K, Q=32/wave, LDS double-buffer via global_load_lds,
// max-free exact softmax, within-wave software pipeline over the two 32-key
// sub-chunks, phase-staggered tile order.
// -------------------------------------------------------------------------
__global__ __launch_bounds__(256, 4) void attn(
    const ushort_t* __restrict__ Ftf, const ushort_t* __restrict__ Gt,
    const ushort_t* __restrict__ Vtf,
    ushort_t* __restrict__ Op, float* __restrict__ ml, int ksplit)
{
    const int b    = blockIdx.z;
    const int part = blockIdx.y;
    const int tid  = threadIdx.x;
    const int lane = tid & 63;
    const int wave = tid >> 6;
    const int l31  = lane & 31;
    const int h2   = lane >> 5;
    const int j0   = blockIdx.x * 128 + wave * 32;
    const int NT   = (N_ / ksplit) / 64;
    const int kt0  = part * NT;
    const int t0   = (blockIdx.x * 5 + part * 3 + b) & (NT - 1);

    __shared__ __align__(16) ushort_t Ks[2][4096];
    __shared__ __align__(16) ushort_t Vs[2][4096];

    const ushort_t* qrow = Gt + ((size_t)b * N_ + j0 + l31) * D_ + 8 * h2;
    const short8 qf0 = *(const short8*)(qrow);
    const short8 qf1 = *(const short8*)(qrow + 16);
    const short8 qf2 = *(const short8*)(qrow + 32);
    const short8 qf3 = *(const short8*)(qrow + 48);

    const ushort_t* Kt = Ftf + ((size_t)b * 64 + kt0) * 4096;
    const ushort_t* Vt = Vtf + ((size_t)b * 64 + kt0) * 4096;

    f32x16 oA, oB;
    #pragma unroll
    for (int q = 0; q < 16; ++q) { oA[q] = 0.f; oB[q] = 0.f; }
    float l_run = 0.f;

    {
        const size_t off = (size_t)t0 * 4096;
        gl16(Kt + off + tid * 8,         &Ks[0][tid * 8]);
        gl16(Kt + off + (tid + 256) * 8, &Ks[0][(tid + 256) * 8]);
        gl16(Vt + off + tid * 8,         &Vs[0][tid * 8]);
        gl16(Vt + off + (tid + 256) * 8, &Vs[0][(tid + 256) * 8]);
    }

    int buf = 0;
    for (int t = 0; t < NT; ++t) {
        __syncthreads();   // drains current tile's DMA (issued a full iter ago)
        if (t + 1 < NT) {
            int nt = t + 1 + t0; if (nt >= NT) nt -= NT;
            const ushort_t* kg = Kt + (size_t)nt * 4096;
            const ushort_t* vg = Vt + (size_t)nt * 4096;
            const int nb = buf ^ 1;
            gl16(kg + tid * 8,         &Ks[nb][tid * 8]);
            gl16(kg + (tid + 256) * 8, &Ks[nb][(tid + 256) * 8]);
            gl16(vg + tid * 8,         &Vs[nb][tid * 8]);
            gl16(vg + (tid + 256) * 8, &Vs[nb][(tid + 256) * 8]);
        }

        const ushort_t* kb0 = &Ks[buf][0];
        const ushort_t* kb1 = &Ks[buf][2048];
        const ushort_t* vb0 = &Vs[buf][0];
        const ushort_t* vb1 = &Vs[buf][2048];

        f32x16 sx0, sx1;
        #pragma unroll
        for (int q = 0; q < 16; ++q) { sx0[q] = 0.f; sx1[q] = 0.f; }
        __builtin_amdgcn_s_setprio(1);
        {
            const short8 ka0 = *(const short8*)(kb0 + 0 * 512 + lane * 8);
            sx0 = __builtin_amdgcn_mfma_f32_32x32x16_bf16(ka0, qf0, sx0, 0, 0, 0);
            const short8 ka1 = *(const short8*)(kb0 + 1 * 512 + lane * 8);
            sx0 = __builtin_amdgcn_mfma_f32_32x32x16_bf16(ka1, qf1, sx0, 0, 0, 0);
            const short8 ka2 = *(const short8*)(kb0 + 2 * 512 + lane * 8);
            sx0 = __builtin_amdgcn_mfma_f32_32x32x16_bf16(ka2, qf2, sx0, 0, 0, 0);
            const short8 ka3 = *(const short8*)(kb0 + 3 * 512 + lane * 8);
            sx0 = __builtin_amdgcn_mfma_f32_32x32x16_bf16(ka3, qf3, sx0, 0, 0, 0);
            const short8 kb0f = *(const short8*)(kb1 + 0 * 512 + lane * 8);
            sx1 = __builtin_amdgcn_mfma_f32_32x32x16_bf16(kb0f, qf0, sx1, 0, 0, 0);
            const short8 kb1f = *(const short8*)(kb1 + 1 * 512 + lane * 8);
            sx1 = __builtin_amdgcn_mfma_f32_32x32x16_bf16(kb1f, qf1, sx1, 0, 0, 0);
            const short8 kb2f = *(const short8*)(kb1 + 2 * 512 + lane * 8);
            sx1 = __builtin_amdgcn_mfma_f32_32x32x16_bf16(kb2f, qf2, sx1, 0, 0, 0);
            const short8 kb3f = *(const short8*)(kb1 + 3 * 512 + lane * 8);
            sx1 = __builtin_amdgcn_mfma_f32_32x32x16_bf16(kb3f, qf3, sx1, 0, 0, 0);
        }
        __builtin_amdgcn_s_setprio(0);

        float cs0 = 0.f;
        union { uint32_t w[4]; short8 v; } p00, p01;
        {
            uint32_t pw[8];
            #pragma unroll
            for (int q = 0; q < 8; ++q) {
                const float pa = __builtin_amdgcn_exp2f(sx0[2 * q]);
                const float pb = __builtin_amdgcn_exp2f(sx0[2 * q + 1]);
                cs0 += pa + pb;
                pw[q] = cvtpk_bf16(pa, pb);
            }
            p00.w[0] = pw[0]; p00.w[1] = pw[1]; p00.w[2] = pw[2]; p00.w[3] = pw[3];
            p01.w[0] = pw[4]; p01.w[1] = pw[5]; p01.w[2] = pw[6]; p01.w[3] = pw[7];
        }

        __builtin_amdgcn_s_setprio(1);
        {
            const short8 v00 = *(const short8*)(vb0 + 0 * 512 + lane * 8);
            oA = __builtin_amdgcn_mfma_f32_32x32x16_bf16(v00, p00.v, oA, 0, 0, 0);
            const short8 v01 = *(const short8*)(vb0 + 1 * 512 + lane * 8);
            oB = __builtin_amdgcn_mfma_f32_32x32x16_bf16(v01, p00.v, oB, 0, 0, 0);
            const short8 v10 = *(const short8*)(vb0 + 2 * 512 + lane * 8);
            oA = __builtin_amdgcn_mfma_f32_32x32x16_bf16(v10, p01.v, oA, 0, 0, 0);
            const short8 v11 = *(const short8*)(vb0 + 3 * 512 + lane * 8);
            oB = __builtin_amdgcn_mfma_f32_32x32x16_bf16(v11, p01.v, oB, 0, 0, 0);
        }
        __builtin_amdgcn_s_setprio(0);

        float cs1 = 0.f;
        union { uint32_t w[4]; short8 v; } p10, p11;
        {
            uint32_t pw[8];
            #pragma unroll
            for (int q = 0; q < 8; ++q) {
                const float pa = __builtin_amdgcn_exp2f(sx1[2 * q]);
                const float pb = __builtin_amdgcn_exp2f(sx1[2 * q + 1]);
                cs1 += pa + pb;
                pw[q] = cvtpk_bf16(pa, pb);
            }
            p10.w[0] = pw[0]; p10.w[1] = pw[1]; p10.w[2] = pw[2]; p10.w[3] = pw[3];
            p11.w[0] = pw[4]; p11.w[1] = pw[5]; p11.w[2] = pw[6]; p11.w[3] = pw[7];
        }

        __builtin_amdgcn_s_setprio(1);
        {
            const short8 v00 = *(const short8*)(vb1 + 0 * 512 + lane * 8);
            oA = __builtin_amdgcn_mfma_f32_32x32x16_bf16(v00, p10.v, oA, 0, 0, 0);
            const short8 v01 = *(const short8*)(vb1 + 1 * 512 + lane * 8);
            oB = __builtin_amdgcn_mfma_f32_32x32x16_bf16(v01, p10.v, oB, 0, 0, 0);
            const short8 v10 = *(const short8*)(vb1 + 2 * 512 + lane * 8);
            oA = __builtin_amdgcn_mfma_f32_32x32x16_bf16(v10, p11.v, oA, 0, 0, 0);
            const short8 v11 = *(const short8*)(vb1 + 3 * 512 + lane * 8);
            oB = __builtin_amdgcn_mfma_f32_32x32x16_bf16(v11, p11.v, oB, 0, 0, 0);
        }
        __builtin_amdgcn_s_setprio(0);

        l_run += cs0 + cs1;
        buf ^= 1;
    }

    const float lt = l_run + __shfl_xor(l_run, 32);

    ushort_t* orow = Op + (((size_t)b * ksplit + part) * N_ + j0 + l31) * D_;
    #pragma unroll
    for (int q = 0; q < 4; ++q) {
        const int d0 = 8 * q + 4 * h2;
        uint2 ua, ub;
        ua.x = cvtpk_bf16(oA[4 * q],     oA[4 * q + 1]);
        ua.y = cvtpk_bf16(oA[4 * q + 2], oA[4 * q + 3]);
        *(uint2*)&orow[d0] = ua;
        ub.x = cvtpk_bf16(oB[4 * q],     oB[4 * q + 1]);
        ub.y = cvtpk_bf16(oB[4 * q + 2], oB[4 * q + 3]);
        *(uint2*)&orow[32 + d0] = ub;
    }
    if (h2 == 0)
        ml[((size_t)b * ksplit + part) * N_ + j0 + l31] = lt;
}

// -------------------------------------------------------------------------
// Kernel 3: fused reduce + outproj (R12 exact — best measured).
// -------------------------------------------------------------------------
__global__ __launch_bounds__(512) void reduce_outproj(
    const ushort_t* __restrict__ Op, const float* __restrict__ ml,
    const float* __restrict__ wv, const float* __restrict__ bv,
    const float* __restrict__ gamma, const float* __restrict__ x,
    float* __restrict__ y, int ksplit)
{
    const int b    = blockIdx.y;
    const int n0   = blockIdx.x * 64;
    const int tid  = threadIdx.x;          // 0..511
    const int wv8  = tid >> 6;             // wave 0..7 -> co rows [wv8*64, +64)
    const int lane = tid & 63;
    const int g    = lane >> 4;
    const int r    = lane & 15;

    __shared__ ushort_t Os[64][72];        // [loc][k] normalized O tile

    {
        const int loc = tid >> 3;          // 0..63
        const int k8  = (tid & 7) * 8;     // 0..56
        float L = 0.f;
        float v[8] = {0.f, 0.f, 0.f, 0.f, 0.f, 0.f, 0.f, 0.f};
        for (int p = 0; p < ksplit; ++p) {
            const size_t base = ((size_t)b * ksplit + p) * N_ + n0 + loc;
            L += ml[base];
            uint4 u = *(const uint4*)&Op[base * D_ + k8];
            v[0] += bf2f(u.x & 0xffffu); v[1] += bf2f(u.x >> 16);
            v[2] += bf2f(u.y & 0xffffu); v[3] += bf2f(u.y >> 16);
            v[4] += bf2f(u.z & 0xffffu); v[5] += bf2f(u.z >> 16);
            v[6] += bf2f(u.w & 0xffffu); v[7] += bf2f(u.w >> 16);
        }
        const float inv = 1.0f / L;
        uint4 o;
        o.x = cvtpk_bf16(v[0] * inv, v[1] * inv);
        o.y = cvtpk_bf16(v[2] * inv, v[3] * inv);
        o.z = cvtpk_bf16(v[4] * inv, v[5] * inv);
        o.w = cvtpk_bf16(v[6] * inv, v[7] * inv);
        *(uint4*)&Os[loc][k8] = o;
    }
    __syncthreads();

    short8 a[4][2];
    #pragma unroll
    for (int cs = 0; cs < 4; ++cs) {
        const float* wrow = wv + (size_t)(wv8 * 64 + cs * 16 + r) * D_ + 8 * g;
        const float4 wa = *(const float4*)(wrow);
        const float4 wb = *(const float4*)(wrow + 4);
        const float4 wc = *(const float4*)(wrow + 32);
        const float4 wd = *(const float4*)(wrow + 36);
        uint32_t* a0 = (uint32_t*)&a[cs][0];
        uint32_t* a1 = (uint32_t*)&a[cs][1];
        a0[0] = cvtpk_bf16(wa.x, wa.y); a0[1] = cvtpk_bf16(wa.z, wa.w);
        a0[2] = cvtpk_bf16(wb.x, wb.y); a0[3] = cvtpk_bf16(wb.z, wb.w);
        a1[0] = cvtpk_bf16(wc.x, wc.y); a1[1] = cvtpk_bf16(wc.z, wc.w);
        a1[2] = cvtpk_bf16(wd.x, wd.y); a1[3] = cvtpk_bf16(wd.z, wd.w);
    }

    f32x4 acc[4][4];
    #pragma unroll
    for (int cs = 0; cs < 4; ++cs)
        #pragma unroll
        for (int t = 0; t < 4; ++t) acc[cs][t] = (f32x4){0.f, 0.f, 0.f, 0.f};

    #pragma unroll
    for (int t = 0; t < 4; ++t) {
        const short8 b0 = *(const short8*)&Os[16 * t + r][8 * g];
        const short8 b1 = *(const short8*)&Os[16 * t + r][32 + 8 * g];
        __builtin_amdgcn_s_setprio(1);
        #pragma unroll
        for (int cs = 0; cs < 4; ++cs) {
            acc[cs][t] = __builtin_amdgcn_mfma_f32_16x16x32_bf16(a[cs][0], b0, acc[cs][t], 0, 0, 0);
            acc[cs][t] = __builtin_amdgcn_mfma_f32_16x16x32_bf16(a[cs][1], b1, acc[cs][t], 0, 0, 0);
        }
        __builtin_amdgcn_s_setprio(0);
    }

    const float gm = *gamma;
    #pragma unroll
    for (int cs = 0; cs < 4; ++cs) {
        #pragma unroll
        for (int t = 0; t < 4; ++t) {
            #pragma unroll
            for (int j = 0; j < 4; ++j) {
                const int co = wv8 * 64 + cs * 16 + 4 * g + j;
                const int n  = n0 + 16 * t + r;
                const size_t idx = ((size_t)b * C_ + co) * N_ + n;
                y[idx] = gm * (acc[cs][t][j] + bv[co]) + x[idx];
            }
        }
    }
}

// -------------------------------------------------------------------------
extern "C" void kernel_launch(void* const* d_in, const int* in_sizes, int n_in,
                              void* d_out, int out_size, void* d_ws, size_t ws_size,
                              hipStream_t stream) {
    const float* x     = (const float*)d_in[0];
    const float* wf    = (const float*)d_in[1];
    const float* bf    = (const float*)d_in[2];
    const float* wg    = (const float*)d_in[3];
    const float* bg    = (const float*)d_in[4];
    const float* wh    = (const float*)d_in[5];
    const float* bh    = (const float*)d_in[6];
    const float* wv    = (const float*)d_in[7];
    const float* bv    = (const float*)d_in[8];
    const float* gamma = (const float*)d_in[9];
    float* y = (float*)d_out;

    const size_t plane = (size_t)B_ * N_ * D_;   // 1M elements
    ushort_t* Ftf = (ushort_t*)d_ws;             // pre-swizzled K fragments
    ushort_t* Gt  = Ftf + plane;                 // Q rows
    ushort_t* Vtf = Gt + plane;                  // pre-swizzled V fragments
    ushort_t* Op  = Vtf + plane;                 // split-K partials (bf16)

    int KS = 8;
    while (KS > 1) {
        const size_t need = 3 * plane * 2 + (size_t)KS * plane * 2
                          + (size_t)B_ * KS * N_ * sizeof(float);
        if (need <= ws_size) break;
        KS >>= 1;
    }
    float* ml = (float*)(Op + (size_t)KS * plane);

    proj_fgh<<<dim3(N_ / 32, B_), 512, 0, stream>>>(
        x, wf, bf, wg, bg, wh, bh, Ftf, Gt, Vtf);
    attn<<<dim3(N_ / 128, KS, B_), 256, 0, stream>>>(
        Ftf, Gt, Vtf, Op, ml, KS);
    reduce_outproj<<<dim3(N_ / 64, B_), 512, 0, stream>>>(
        Op, ml, wv, bv, gamma, x, y, KS);
}